// Round 5
// baseline (306.315 us; speedup 1.0000x reference)
//
#include <hip/hip_runtime.h>

#define Vv 30
#define Tt 8192
#define Kk 5
#define Ll 512
#define Bb 32
#define NVK 150            // real rows (v*5+k)
#define ZROW 150           // zero row
#define NROWS 151
#define TPOS (Bb * Ll)     // 16384 positions
#define NC4 2048           // fine chunks (4 t each)
#define NC32 256           // coarse chunks (32 t each)
#define PG 32              // position groups (512 pos each)
#define PPB (TPOS / PG)
#define PPT 2              // positions per thread
#define TRm 16             // chunk-ranges for main scan
#define CPR (NC4 / TRm)    // 128 chunks per range
#define TCH 64             // chunks per LDS tile
#define NTILE (CPR / TCH)  // 2
#define LSG 17             // LDS granule stride (16 + 1 pad)
#define NPART 17           // 16 range partials + 1 seed

__device__ inline float4 add4(float4 a, float4 b) {
    return make_float4(a.x + b.x, a.y + b.y, a.z + b.z, a.w + b.w);
}
// canonical tree: ((r0+r1)+(r2+r3))+r4  -- used EVERYWHERE (monotone => exact ub)
__device__ inline float4 tree5(float4 a, float4 b, float4 c, float4 d, float4 e) {
    return add4(add4(add4(a, b), add4(c, d)), e);
}

// ---------------------------------------------------------------------------
// Kernel 1: wt transpose (bias folded into k==2), cm4 + cm32 chunk-max tables.
// Grid: 256 x 256.
// ---------------------------------------------------------------------------
__global__ __launch_bounds__(256) void prep_w(
    const float* __restrict__ conv_w,
    const float* __restrict__ conv_b,
    float* __restrict__ wt,
    float* __restrict__ cm4,
    float* __restrict__ cm32)
{
    __shared__ float tile[32 * NVK];     // 19.2 KB
    __shared__ float cml[NROWS * 8];     // 4.8 KB

    const int t0 = blockIdx.x * 32;
    const int tid = threadIdx.x;

    for (int i = tid; i < 32 * NVK; i += 256)
        tile[i] = conv_w[t0 * NVK + i];
    __syncthreads();

    // wt[vk][t] with bias folded
    for (int i = tid; i < NVK * 32; i += 256) {
        const int vk = i >> 5;
        const int tl = i & 31;
        float v = tile[tl * NVK + vk];
        const int k = vk - (vk / Kk) * Kk;
        if (k == 2) v += conv_b[t0 + tl];
        wt[vk * Tt + t0 + tl] = v;
    }
    if (tid < 32) wt[ZROW * Tt + t0 + tid] = 0.0f;

    // cm4: max over 4 t (bias included)
    for (int idx = tid; idx < NROWS * 8; idx += 256) {
        const int row = idx >> 3;
        const int cj  = idx & 7;
        float m;
        if (row == ZROW) {
            m = 0.0f;
        } else {
            const int k = row - (row / Kk) * Kk;
            m = -1e30f;
#pragma unroll
            for (int q = 0; q < 4; ++q) {
                const int tl = cj * 4 + q;
                float v = tile[tl * NVK + row];
                if (k == 2) v += conv_b[t0 + tl];
                m = fmaxf(m, v);
            }
        }
        cm4[row * NC4 + (t0 >> 2) + cj] = m;
        cml[idx] = m;
    }
    __syncthreads();

    // cm32: max over this block's 32 t (== one coarse chunk)
    for (int row = tid; row < NROWS; row += 256) {
        float m = cml[row * 8];
#pragma unroll
        for (int q = 1; q < 8; ++q) m = fmaxf(m, cml[row * 8 + q]);
        cm32[row * NC32 + blockIdx.x] = m;
    }
}

// ---------------------------------------------------------------------------
// Kernel 2 (seed): one wave per position. Coarse ub scan (256 chunks) ->
// exact eval of best 32-t window -> lb[pos] + seed partial.
// Grid: TPOS/4 = 4096 blocks x 256.
// ---------------------------------------------------------------------------
__global__ __launch_bounds__(256) void seed_k(
    const int* __restrict__ seq,
    const float* __restrict__ wt,
    const float* __restrict__ cm32,
    float* __restrict__ lb,
    float2* __restrict__ partials)
{
    const int lane = threadIdx.x & 63;
    const int pos  = blockIdx.x * 4 + (threadIdx.x >> 6);
    const int b = pos >> 9;
    const int l = pos & (Ll - 1);

    int rows[Kk];
#pragma unroll
    for (int k = 0; k < Kk; ++k) {
        const int lp = l + k - 2;
        rows[k] = (lp >= 0 && lp < Ll) ? (seq[b * Ll + lp] * Kk + k) : ZROW;
    }

    // coarse ub: lane handles coarse chunks 4*lane..4*lane+3
    const float4* __restrict__ c32_4 = (const float4*)cm32;   // row stride 64 granules
    const float4 u = tree5(c32_4[rows[0] * 64 + lane], c32_4[rows[1] * 64 + lane],
                           c32_4[rows[2] * 64 + lane], c32_4[rows[3] * 64 + lane],
                           c32_4[rows[4] * 64 + lane]);
    float mu = u.x; int mc = lane * 4;
    if (u.y > mu) { mu = u.y; mc = lane * 4 + 1; }
    if (u.z > mu) { mu = u.z; mc = lane * 4 + 2; }
    if (u.w > mu) { mu = u.w; mc = lane * 4 + 3; }
#pragma unroll
    for (int m = 32; m >= 1; m >>= 1) {
        const float om = __shfl_xor(mu, m);
        const int   oc = __shfl_xor(mc, m);
        if (om > mu || (om == mu && oc < mc)) { mu = om; mc = oc; }
    }

    // exact eval of the 32 t in coarse chunk mc (both half-waves duplicate)
    const int t = mc * 32 + (lane & 31);
    const float w0 = wt[rows[0] * Tt + t];
    const float w1 = wt[rows[1] * Tt + t];
    const float w2 = wt[rows[2] * Tt + t];
    const float w3 = wt[rows[3] * Tt + t];
    const float w4 = wt[rows[4] * Tt + t];
    float bv = ((w0 + w1) + (w2 + w3)) + w4;
    int   bt = t;
#pragma unroll
    for (int m = 32; m >= 1; m >>= 1) {
        const float ov = __shfl_xor(bv, m);
        const int   ot = __shfl_xor(bt, m);
        if (ov > bv || (ov == bv && ot < bt)) { bv = ov; bt = ot; }
    }

    if (lane == 0) {
        lb[pos] = bv;
        partials[16 * TPOS + pos] = make_float2(bv, __int_as_float(bt));
    }
}

// ---------------------------------------------------------------------------
// Kernel 3 (main): LDS-tiled scan of cm4 with survivor drain.
// Grid: PG*TRm = 512 blocks x 256 threads. Block (pg,tr): 512 positions x
// 128 chunks, tiles of [151 rows x 64 chunks] in LDS.
// ---------------------------------------------------------------------------
__global__ __launch_bounds__(256) void conv_scan(
    const int* __restrict__ seq,
    const float* __restrict__ wt,
    const float* __restrict__ cm4,
    const float* __restrict__ lb,
    float2* __restrict__ partials)
{
    __shared__ float4 tile4[NROWS * LSG];   // 41 KB

    const int bid = blockIdx.x;
    const int pg  = bid & (PG - 1);
    const int tr  = bid >> 5;
    const int tid = threadIdx.x;

    int rows[PPT][Kk];
    int f4off[PPT][Kk];
    float lbv[PPT];
#pragma unroll
    for (int j = 0; j < PPT; ++j) {
        const int pos = pg * PPB + j * 256 + tid;
        const int b = pos >> 9;
        const int l = pos & (Ll - 1);
#pragma unroll
        for (int k = 0; k < Kk; ++k) {
            const int lp = l + k - 2;
            const int row = (lp >= 0 && lp < Ll) ? (seq[b * Ll + lp] * Kk + k) : ZROW;
            rows[j][k]  = row;
            f4off[j][k] = row * LSG;
        }
        lbv[j] = lb[pos];
    }

    float bv[PPT];
    int   bt[PPT];
#pragma unroll
    for (int j = 0; j < PPT; ++j) { bv[j] = -1e30f; bt[j] = 0; }

    const float4* __restrict__ cm4_4 = (const float4*)cm4;  // row stride 512 granules
    const float4* __restrict__ wt4   = (const float4*)wt;   // row stride 2048 granules

    for (int tl = 0; tl < NTILE; ++tl) {
        const int cbase = tr * CPR + tl * TCH;   // first chunk of this tile
        const int gbase = cbase >> 2;            // granule base in cm4 row

        __syncthreads();
        for (int i = tid; i < NROWS * 16; i += 256) {
            const int row = i >> 4;
            const int col = i & 15;
            tile4[row * LSG + col] = cm4_4[row * 512 + gbase + col];
        }
        __syncthreads();

        unsigned long long mask[PPT] = {0ull, 0ull};

#pragma unroll 4
        for (int g = 0; g < 16; ++g) {
#pragma unroll
            for (int j = 0; j < PPT; ++j) {
                const float4 u = tree5(tile4[f4off[j][0] + g], tile4[f4off[j][1] + g],
                                       tile4[f4off[j][2] + g], tile4[f4off[j][3] + g],
                                       tile4[f4off[j][4] + g]);
                unsigned long long bits =
                    (unsigned long long)((u.x >= lbv[j]) ? 1u : 0u)
                  | ((unsigned long long)((u.y >= lbv[j]) ? 1u : 0u) << 1)
                  | ((unsigned long long)((u.z >= lbv[j]) ? 1u : 0u) << 2)
                  | ((unsigned long long)((u.w >= lbv[j]) ? 1u : 0u) << 3);
                mask[j] |= bits << (g * 4);
            }
        }

        // Drain survivors (rare): exact eval from global wt, min-t tie-break.
#pragma unroll
        for (int j = 0; j < PPT; ++j) {
            unsigned long long m = mask[j];
            while (m) {
                const int bidx = __ffsll(m) - 1;
                m &= m - 1;
                const int c = cbase + bidx;
                const float4 e = tree5(wt4[rows[j][0] * 512 * 4 + c],
                                       wt4[rows[j][1] * 512 * 4 + c],
                                       wt4[rows[j][2] * 512 * 4 + c],
                                       wt4[rows[j][3] * 512 * 4 + c],
                                       wt4[rows[j][4] * 512 * 4 + c]);
                int t = c * 4;
                if (e.x > bv[j] || (e.x == bv[j] && t < bt[j])) { bv[j] = e.x; bt[j] = t; }
                t = c * 4 + 1;
                if (e.y > bv[j] || (e.y == bv[j] && t < bt[j])) { bv[j] = e.y; bt[j] = t; }
                t = c * 4 + 2;
                if (e.z > bv[j] || (e.z == bv[j] && t < bt[j])) { bv[j] = e.z; bt[j] = t; }
                t = c * 4 + 3;
                if (e.w > bv[j] || (e.w == bv[j] && t < bt[j])) { bv[j] = e.w; bt[j] = t; }
            }
        }
    }

#pragma unroll
    for (int j = 0; j < PPT; ++j) {
        const int pos = pg * PPB + j * 256 + tid;
        partials[tr * TPOS + pos] = make_float2(bv[j], __int_as_float(bt[j]));
    }
}

// ---------------------------------------------------------------------------
// Kernel 4: combine 16 range partials + seed (min-t tie-break).
// ---------------------------------------------------------------------------
__global__ __launch_bounds__(256) void combine(
    const float2* __restrict__ partials,
    int* __restrict__ out)
{
    const int pos = blockIdx.x * 256 + threadIdx.x;
    float bv = -1e30f;
    int   bt = 0x7fffffff;
#pragma unroll
    for (int i = 0; i < NPART; ++i) {
        const float2 p = partials[i * TPOS + pos];
        const int t = __float_as_int(p.y);
        if (p.x > bv || (p.x == bv && t < bt)) { bv = p.x; bt = t; }
    }
    out[pos] = bt;
}

// ---------------------------------------------------------------------------
extern "C" void kernel_launch(void* const* d_in, const int* in_sizes, int n_in,
                              void* d_out, int out_size, void* d_ws, size_t ws_size,
                              hipStream_t stream)
{
    const int*   seq    = (const int*)d_in[0];
    const float* conv_w = (const float*)d_in[1];
    const float* conv_b = (const float*)d_in[2];
    int*         out    = (int*)d_out;

    float* wt   = (float*)d_ws;                         // 151*8192
    float* cm4  = wt  + (size_t)NROWS * Tt;             // 151*2048
    float* cm32 = cm4 + (size_t)NROWS * NC4;            // 151*256
    float* lbp  = cm32 + (size_t)NROWS * NC32;          // 16384
    float2* part = (float2*)(lbp + TPOS);               // 17*16384 float2

    prep_w<<<Tt / 32, 256, 0, stream>>>(conv_w, conv_b, wt, cm4, cm32);
    seed_k<<<TPOS / 4, 256, 0, stream>>>(seq, wt, cm32, lbp, part);
    conv_scan<<<PG * TRm, 256, 0, stream>>>(seq, wt, cm4, lbp, part);
    combine<<<TPOS / 256, 256, 0, stream>>>(part, out);
}

// Round 7
// 150.338 us; speedup vs baseline: 2.0375x; 2.0375x over previous
//
#include <hip/hip_runtime.h>
#include <hip/hip_fp16.h>

#define Vv 30
#define Tt 8192
#define Kk 5
#define Ll 512
#define Bb 32
#define NVK 150            // real rows (v*5+k)
#define ZROW 150           // zero row
#define NROWS 151
#define TPOS (Bb * Ll)     // 16384 positions
#define NC32 256           // coarse chunks (32 t) for seed
#define PG 32              // position groups (512 pos each)
#define PPB (TPOS / PG)
#define PPT 2
#define TRm 16             // t-ranges
#define TW (Tt / TRm)      // 512 t per range
#define GPT 16             // 8-t granules per LDS tile (128 t)
#define NTILE 4            // tiles per range
#define LSG 17             // LDS granule stride (16B units), odd for bank spread
#define NPART 17           // 16 range partials + seed

__device__ inline float4 add4(float4 a, float4 b) {
    return make_float4(a.x + b.x, a.y + b.y, a.z + b.z, a.w + b.w);
}
__device__ inline float4 tree5(float4 a, float4 b, float4 c, float4 d, float4 e) {
    return add4(add4(add4(a, b), add4(c, d)), e);
}
__device__ inline __half2 bc_h2(float x) { return __builtin_bit_cast(__half2, x); }

// ---------------------------------------------------------------------------
// Kernel 1: wt fp32 + wh f16 (bias folded into k==2), cm32 table, wmax.
// Grid: 256 x 256.
// ---------------------------------------------------------------------------
__global__ __launch_bounds__(256) void prep_w(
    const float* __restrict__ conv_w,
    const float* __restrict__ conv_b,
    float* __restrict__ wt,
    __half* __restrict__ wh,
    float* __restrict__ cm32,
    unsigned* __restrict__ wmax)
{
    __shared__ float tile[32 * NVK];     // 19.2 KB
    const int t0 = blockIdx.x * 32;
    const int tid = threadIdx.x;

    for (int i = tid; i < 32 * NVK; i += 256)
        tile[i] = conv_w[t0 * NVK + i];
    __syncthreads();

    float amax = 0.0f;
    for (int i = tid; i < NVK * 32; i += 256) {
        const int vk = i >> 5;
        const int tl = i & 31;
        float v = tile[tl * NVK + vk];
        const int k = vk - (vk / Kk) * Kk;
        if (k == 2) v += conv_b[t0 + tl];
        wt[vk * Tt + t0 + tl] = v;
        wh[vk * Tt + t0 + tl] = __float2half(v);
        amax = fmaxf(amax, fabsf(v));
    }
    if (tid < 32) {
        wt[ZROW * Tt + t0 + tid] = 0.0f;
        wh[ZROW * Tt + t0 + tid] = __float2half(0.0f);
    }

    // wave-reduce amax -> one atomic per wave (all values >= 0: u32 monotone)
#pragma unroll
    for (int m = 32; m >= 1; m >>= 1)
        amax = fmaxf(amax, __shfl_xor(amax, m));
    if ((tid & 63) == 0) atomicMax(wmax, __float_as_uint(amax));

    // cm32: per-row max over this block's 32 t
    for (int row = tid; row < NROWS; row += 256) {
        float m;
        if (row == ZROW) {
            m = 0.0f;
        } else {
            const int k = row - (row / Kk) * Kk;
            m = -1e30f;
            for (int tl = 0; tl < 32; ++tl) {
                float v = tile[tl * NVK + row];
                if (k == 2) v += conv_b[t0 + tl];
                m = fmaxf(m, v);
            }
        }
        cm32[row * NC32 + blockIdx.x] = m;
    }
}

// ---------------------------------------------------------------------------
// Kernel 2 (seed): one wave per position. Top-2 coarse-ub windows, exact-eval
// both (32 lanes each) -> lb[pos] + seed partial. Grid: TPOS/4 x 256.
// ---------------------------------------------------------------------------
__global__ __launch_bounds__(256) void seed_k(
    const int* __restrict__ seq,
    const float* __restrict__ wt,
    const float* __restrict__ cm32,
    float* __restrict__ lb,
    float2* __restrict__ partials)
{
    const int lane = threadIdx.x & 63;
    const int pos  = blockIdx.x * 4 + (threadIdx.x >> 6);
    const int b = pos >> 9;
    const int l = pos & (Ll - 1);

    int rows[Kk];
#pragma unroll
    for (int k = 0; k < Kk; ++k) {
        const int lp = l + k - 2;
        rows[k] = (lp >= 0 && lp < Ll) ? (seq[b * Ll + lp] * Kk + k) : ZROW;
    }

    const float4* __restrict__ c32_4 = (const float4*)cm32;   // 64 granules/row
    const float4 u = tree5(c32_4[rows[0] * 64 + lane], c32_4[rows[1] * 64 + lane],
                           c32_4[rows[2] * 64 + lane], c32_4[rows[3] * 64 + lane],
                           c32_4[rows[4] * 64 + lane]);
    const float uv[4] = {u.x, u.y, u.z, u.w};

    // top-1 window
    float mu = -1e30f; int mc = 0;
#pragma unroll
    for (int s = 0; s < 4; ++s) {
        const int c = lane * 4 + s;
        if (uv[s] > mu || (uv[s] == mu && c < mc)) { mu = uv[s]; mc = c; }
    }
#pragma unroll
    for (int m = 32; m >= 1; m >>= 1) {
        const float om = __shfl_xor(mu, m);
        const int   oc = __shfl_xor(mc, m);
        if (om > mu || (om == mu && oc < mc)) { mu = om; mc = oc; }
    }
    // top-2 window
    float mu2 = -1e30f; int mc2 = 0;
#pragma unroll
    for (int s = 0; s < 4; ++s) {
        const int c = lane * 4 + s;
        const float v = (c == mc) ? -1e30f : uv[s];
        if (v > mu2 || (v == mu2 && c < mc2)) { mu2 = v; mc2 = c; }
    }
#pragma unroll
    for (int m = 32; m >= 1; m >>= 1) {
        const float om = __shfl_xor(mu2, m);
        const int   oc = __shfl_xor(mc2, m);
        if (om > mu2 || (om == mu2 && oc < mc2)) { mu2 = om; mc2 = oc; }
    }

    // exact eval: lanes 0-31 -> window mc, lanes 32-63 -> window mc2
    const int wsel = (lane < 32) ? mc : mc2;
    const int t = wsel * 32 + (lane & 31);
    const float w0 = wt[rows[0] * Tt + t];
    const float w1 = wt[rows[1] * Tt + t];
    const float w2 = wt[rows[2] * Tt + t];
    const float w3 = wt[rows[3] * Tt + t];
    const float w4 = wt[rows[4] * Tt + t];
    float bv = ((w0 + w1) + (w2 + w3)) + w4;
    int   bt = t;
#pragma unroll
    for (int m = 32; m >= 1; m >>= 1) {
        const float ov = __shfl_xor(bv, m);
        const int   ot = __shfl_xor(bt, m);
        if (ov > bv || (ov == bv && ot < bt)) { bv = ov; bt = ot; }
    }

    if (lane == 0) {
        lb[pos] = bv;
        partials[16 * TPOS + pos] = make_float2(bv, __int_as_float(bt));
    }
}

// ---------------------------------------------------------------------------
// Kernel 3 (main): f16 LDS-tiled scan, 8 t per ds_read_b128 per tap.
// Granules with approx-max >= R - TWO_E are exact-verified from global wt.
// Guarantee: |sa - s| <= E <= 0.0122*wmax < TWO_E/2, R starts at exact lb,
// so the true argmax granule is always marked. Grid: PG*TRm = 512 x 256.
// ---------------------------------------------------------------------------
__global__ __launch_bounds__(256) void conv_scan16(
    const int* __restrict__ seq,
    const float* __restrict__ wt,
    const __half* __restrict__ wh,
    const float* __restrict__ lb,
    const unsigned* __restrict__ wmax,
    float2* __restrict__ partials)
{
    __shared__ float4 tile4[NROWS * LSG];   // 41.1 KB (f16 data: 8 t / float4)

    const int bid = blockIdx.x;
    const int pg  = bid & (PG - 1);
    const int tr  = bid >> 5;
    const int tid = threadIdx.x;

    const float TWO_E = 0.05f * fmaxf(__uint_as_float(wmax[0]), 1e-6f);

    int rows[PPT][Kk];
    int foff[PPT][Kk];
    float R[PPT];          // running approx max, seeded with exact lb
#pragma unroll
    for (int j = 0; j < PPT; ++j) {
        const int pos = pg * PPB + j * 256 + tid;
        const int b = pos >> 9;
        const int l = pos & (Ll - 1);
#pragma unroll
        for (int k = 0; k < Kk; ++k) {
            const int lp = l + k - 2;
            const int row = (lp >= 0 && lp < Ll) ? (seq[b * Ll + lp] * Kk + k) : ZROW;
            rows[j][k] = row;
            foff[j][k] = row * LSG;
        }
        R[j] = lb[pos];
    }

    float bv[PPT];
    int   bt[PPT];
#pragma unroll
    for (int j = 0; j < PPT; ++j) { bv[j] = -1e30f; bt[j] = 0; }

    const float4* __restrict__ wh4 = (const float4*)wh;   // 1024 granules/row
    const float4* __restrict__ wt4 = (const float4*)wt;   // 2048 float4/row

    for (int tl = 0; tl < NTILE; ++tl) {
        const int g0 = tr * (TW / 8) + tl * GPT;    // 8-t granule base in row

        __syncthreads();
        for (int i = tid; i < NROWS * GPT; i += 256) {
            const int row = i >> 4;
            const int col = i & 15;
            tile4[row * LSG + col] = wh4[row * 1024 + g0 + col];
        }
        __syncthreads();

        unsigned mask = 0;   // bit j*16+g

#pragma unroll 4
        for (int g = 0; g < GPT; ++g) {
#pragma unroll
            for (int j = 0; j < PPT; ++j) {
                const float4 q0 = tile4[foff[j][0] + g];
                const float4 q1 = tile4[foff[j][1] + g];
                const float4 q2 = tile4[foff[j][2] + g];
                const float4 q3 = tile4[foff[j][3] + g];
                const float4 q4 = tile4[foff[j][4] + g];
                // 4 half2 slots x 5 taps, packed adds
                const __half2 s0 = __hadd2(__hadd2(__hadd2(bc_h2(q0.x), bc_h2(q1.x)),
                                                   __hadd2(bc_h2(q2.x), bc_h2(q3.x))), bc_h2(q4.x));
                const __half2 s1 = __hadd2(__hadd2(__hadd2(bc_h2(q0.y), bc_h2(q1.y)),
                                                   __hadd2(bc_h2(q2.y), bc_h2(q3.y))), bc_h2(q4.y));
                const __half2 s2 = __hadd2(__hadd2(__hadd2(bc_h2(q0.z), bc_h2(q1.z)),
                                                   __hadd2(bc_h2(q2.z), bc_h2(q3.z))), bc_h2(q4.z));
                const __half2 s3 = __hadd2(__hadd2(__hadd2(bc_h2(q0.w), bc_h2(q1.w)),
                                                   __hadd2(bc_h2(q2.w), bc_h2(q3.w))), bc_h2(q4.w));
                // float-domain max (no __hmax2 in ROCm 7.2 headers)
                const float2 f0 = __half22float2(s0);
                const float2 f1 = __half22float2(s1);
                const float2 f2 = __half22float2(s2);
                const float2 f3 = __half22float2(s3);
                const float gl = fmaxf(fmaxf(fmaxf(f0.x, f0.y), fmaxf(f1.x, f1.y)),
                                       fmaxf(fmaxf(f2.x, f2.y), fmaxf(f3.x, f3.y)));
                R[j] = fmaxf(R[j], gl);
                if (gl >= R[j] - TWO_E) mask |= 1u << (j * 16 + g);
            }
        }

        // drain marked granules: exact fp32 eval (8 t each) from global wt
#pragma unroll
        for (int j = 0; j < PPT; ++j) {
            unsigned m = (mask >> (j * 16)) & 0xFFFFu;
            while (m) {
                const int g = __ffs(m) - 1;
                m &= m - 1;
                const int gc = g0 + g;          // global 8-t granule
                const float4 eA = tree5(wt4[rows[j][0] * 2048 + 2 * gc],
                                        wt4[rows[j][1] * 2048 + 2 * gc],
                                        wt4[rows[j][2] * 2048 + 2 * gc],
                                        wt4[rows[j][3] * 2048 + 2 * gc],
                                        wt4[rows[j][4] * 2048 + 2 * gc]);
                const float4 eB = tree5(wt4[rows[j][0] * 2048 + 2 * gc + 1],
                                        wt4[rows[j][1] * 2048 + 2 * gc + 1],
                                        wt4[rows[j][2] * 2048 + 2 * gc + 1],
                                        wt4[rows[j][3] * 2048 + 2 * gc + 1],
                                        wt4[rows[j][4] * 2048 + 2 * gc + 1]);
                const int t0 = gc * 8;
                const float ev[8] = {eA.x, eA.y, eA.z, eA.w, eB.x, eB.y, eB.z, eB.w};
#pragma unroll
                for (int q = 0; q < 8; ++q) {
                    const int t = t0 + q;
                    if (ev[q] > bv[j] || (ev[q] == bv[j] && t < bt[j])) { bv[j] = ev[q]; bt[j] = t; }
                }
            }
        }
    }

#pragma unroll
    for (int j = 0; j < PPT; ++j) {
        const int pos = pg * PPB + j * 256 + tid;
        partials[tr * TPOS + pos] = make_float2(bv[j], __int_as_float(bt[j]));
    }
}

// ---------------------------------------------------------------------------
// Kernel 4: combine 16 range partials + seed (min-t tie-break).
// ---------------------------------------------------------------------------
__global__ __launch_bounds__(256) void combine(
    const float2* __restrict__ partials,
    int* __restrict__ out)
{
    const int pos = blockIdx.x * 256 + threadIdx.x;
    float bv = -1e30f;
    int   bt = 0x7fffffff;
#pragma unroll
    for (int i = 0; i < NPART; ++i) {
        const float2 p = partials[i * TPOS + pos];
        const int t = __float_as_int(p.y);
        if (p.x > bv || (p.x == bv && t < bt)) { bv = p.x; bt = t; }
    }
    out[pos] = bt;
}

// ---------------------------------------------------------------------------
extern "C" void kernel_launch(void* const* d_in, const int* in_sizes, int n_in,
                              void* d_out, int out_size, void* d_ws, size_t ws_size,
                              hipStream_t stream)
{
    const int*   seq    = (const int*)d_in[0];
    const float* conv_w = (const float*)d_in[1];
    const float* conv_b = (const float*)d_in[2];
    int*         out    = (int*)d_out;

    float*    wt   = (float*)d_ws;                            // 151*8192 f32
    __half*   wh   = (__half*)(wt + (size_t)NROWS * Tt);      // 151*8192 f16
    float*    cm32 = (float*)(wh + (size_t)NROWS * Tt);       // 151*256 f32
    float*    lbp  = cm32 + (size_t)NROWS * NC32;             // 16384 f32
    float2*   part = (float2*)(lbp + TPOS);                   // 17*16384 float2
    unsigned* wmax = (unsigned*)(part + (size_t)NPART * TPOS);// 1 u32

    (void)hipMemsetAsync(wmax, 0, sizeof(unsigned), stream);
    prep_w<<<Tt / 32, 256, 0, stream>>>(conv_w, conv_b, wt, wh, cm32, wmax);
    seed_k<<<TPOS / 4, 256, 0, stream>>>(seq, wt, cm32, lbp, part);
    conv_scan16<<<PG * TRm, 256, 0, stream>>>(seq, wt, wh, lbp, wmax, part);
    combine<<<TPOS / 256, 256, 0, stream>>>(part, out);
}